// Round 1
// baseline (329.211 us; speedup 1.0000x reference)
//
#include <hip/hip_runtime.h>

// Problem: B=32, NC=4, H=512, W=512, fp32 in, two fp32 scalars out.
// lseg = mean BCE-with-logits; liou = 1 - mean_b( sum_c IoU(b,c) / present(b) ).

#define NB   32
#define NCL  4
constexpr int HW      = 512 * 512;       // 262144 pixels per (b,c) plane
constexpr int GROUPS  = HW / 4;          // 65536 float4-groups per batch
constexpr int THREADS = 256;
constexpr int BLOCKS_PER_BATCH = 64;
constexpr int TPB = BLOCKS_PER_BATCH * THREADS;   // 16384 threads per batch
constexpr int ITERS = GROUPS / TPB;               // 4 groups (16 pixels) per thread

__global__ __launch_bounds__(THREADS)
void seg_main(const float* __restrict__ pred,
              const float* __restrict__ tgt,
              float* __restrict__ bce_sum,
              unsigned* __restrict__ pc_g,   // [NB][NCL] pred counts
              unsigned* __restrict__ tc_g,   // [NB][NCL] tgt counts
              unsigned* __restrict__ tp_g)   // [NB][NCL] true positives
{
    const int b     = blockIdx.x & (NB - 1);       // one batch per block
    const int chunk = blockIdx.x >> 5;             // 0..63
    const int tib   = chunk * THREADS + threadIdx.x;
    const size_t base_b = (size_t)b * NCL * HW;

    float bce = 0.0f;
    unsigned pc[NCL] = {0, 0, 0, 0};
    unsigned tc[NCL] = {0, 0, 0, 0};
    unsigned tp[NCL] = {0, 0, 0, 0};

    for (int it = 0; it < ITERS; ++it) {
        const size_t off = base_b + 4u * (size_t)(tib + it * TPB);
        float4 pv[NCL], tv[NCL];
#pragma unroll
        for (int c = 0; c < NCL; ++c) {
            pv[c] = *reinterpret_cast<const float4*>(pred + off + (size_t)c * HW);
            tv[c] = *reinterpret_cast<const float4*>(tgt  + off + (size_t)c * HW);
        }
#pragma unroll
        for (int j = 0; j < 4; ++j) {
            float pj[NCL], tj[NCL];
#pragma unroll
            for (int c = 0; c < NCL; ++c) {
                pj[c] = (&pv[c].x)[j];
                tj[c] = (&tv[c].x)[j];
            }
            // first-occurrence argmax (strict >) matches jnp.argmax
            int cp = 0, ct = 0;
            float bp = pj[0], bt = tj[0];
#pragma unroll
            for (int c = 1; c < NCL; ++c) {
                if (pj[c] > bp) { bp = pj[c]; cp = c; }
                if (tj[c] > bt) { bt = tj[c]; ct = c; }
            }
#pragma unroll
            for (int c = 0; c < NCL; ++c) {
                pc[c] += (cp == c);
                tc[c] += (ct == c);
                tp[c] += ((cp == c) & (ct == c));
            }
            // BCE with logits, numerically stable
#pragma unroll
            for (int c = 0; c < NCL; ++c) {
                const float p = pj[c];
                bce += fmaxf(p, 0.0f) - p * tj[c]
                     + __logf(1.0f + __expf(-fabsf(p)));
            }
        }
    }

    // Pack 12 counters (each <=16 per thread, <=1024 after 64-lane sum) into
    // three u64 with 16-bit fields; butterfly-reduce across the wave.
    unsigned long long P = (unsigned long long)pc[0]
                         | ((unsigned long long)pc[1] << 16)
                         | ((unsigned long long)pc[2] << 32)
                         | ((unsigned long long)pc[3] << 48);
    unsigned long long T = (unsigned long long)tc[0]
                         | ((unsigned long long)tc[1] << 16)
                         | ((unsigned long long)tc[2] << 32)
                         | ((unsigned long long)tc[3] << 48);
    unsigned long long Q = (unsigned long long)tp[0]
                         | ((unsigned long long)tp[1] << 16)
                         | ((unsigned long long)tp[2] << 32)
                         | ((unsigned long long)tp[3] << 48);
#pragma unroll
    for (int o = 32; o > 0; o >>= 1) {
        bce += __shfl_xor(bce, o);
        P   += __shfl_xor(P, o);
        T   += __shfl_xor(T, o);
        Q   += __shfl_xor(Q, o);
    }
    if ((threadIdx.x & 63) == 0) {
        atomicAdd(bce_sum, bce);
#pragma unroll
        for (int c = 0; c < NCL; ++c) {
            atomicAdd(&pc_g[b * NCL + c], (unsigned)((P >> (16 * c)) & 0xFFFFu));
            atomicAdd(&tc_g[b * NCL + c], (unsigned)((T >> (16 * c)) & 0xFFFFu));
            atomicAdd(&tp_g[b * NCL + c], (unsigned)((Q >> (16 * c)) & 0xFFFFu));
        }
    }
}

__global__ void seg_final(const float* __restrict__ bce_sum,
                          const unsigned* __restrict__ pc_g,
                          const unsigned* __restrict__ tc_g,
                          const unsigned* __restrict__ tp_g,
                          float* __restrict__ out)
{
    const int t = threadIdx.x;
    float val = 0.0f;
    if (t < NB) {
        float iou = 0.0f;
        int present = 0;
#pragma unroll
        for (int c = 0; c < NCL; ++c) {
            const float P = (float)pc_g[t * NCL + c];
            const float T = (float)tc_g[t * NCL + c];
            const float K = (float)tp_g[t * NCL + c];
            const float den = P + T - K;
            if (den > 0.0f) iou += K / den;
            present += (tc_g[t * NCL + c] > 0u);
        }
        val = iou / (float)present;   // present >= 1 always (sum_c tgt_cnt = HW)
    }
#pragma unroll
    for (int o = 32; o > 0; o >>= 1) val += __shfl_xor(val, o);
    if (t == 0) {
        out[0] = bce_sum[0] / (float)((size_t)NB * NCL * HW);  // lseg
        out[1] = 1.0f - val / (float)NB;                       // liou
    }
}

extern "C" void kernel_launch(void* const* d_in, const int* in_sizes, int n_in,
                              void* d_out, int out_size, void* d_ws, size_t ws_size,
                              hipStream_t stream) {
    const float* pred = (const float*)d_in[0];
    const float* tgt  = (const float*)d_in[1];
    float* out = (float*)d_out;

    // workspace layout: [0,4): bce_sum (float); [256,...): 3 x 128 uint counters
    float*    bce_sum = (float*)d_ws;
    unsigned* pc_g    = (unsigned*)((char*)d_ws + 256);
    unsigned* tc_g    = pc_g + NB * NCL;
    unsigned* tp_g    = tc_g + NB * NCL;

    hipMemsetAsync(d_ws, 0, 256 + 3 * NB * NCL * sizeof(unsigned), stream);
    seg_main<<<NB * BLOCKS_PER_BATCH, THREADS, 0, stream>>>(pred, tgt, bce_sum,
                                                            pc_g, tc_g, tp_g);
    seg_final<<<1, 64, 0, stream>>>(bce_sum, pc_g, tc_g, tp_g, out);
}

// Round 2
// 316.763 us; speedup vs baseline: 1.0393x; 1.0393x over previous
//
#include <hip/hip_runtime.h>

// Problem: B=32, NC=4, H=512, W=512, fp32 in, two fp32 scalars out.
// lseg = mean BCE-with-logits; liou = 1 - mean_b( sum_c IoU(b,c) / present(b) ).
//
// R1 analysis: 32-VGPR compile serialized the 8 loads/iter -> latency-bound
// (~1.2 TB/s effective). Fix: __launch_bounds__(256,4) for a 128-VGPR budget +
// explicit double-buffered load pipeline (all 8 loads of iter k+1 in flight
// while computing iter k).

#define NB   32
#define NCL  4
constexpr int HW      = 512 * 512;       // 262144 pixels per (b,c) plane
constexpr int GROUPS  = HW / 4;          // 65536 float4-groups per batch
constexpr int THREADS = 256;
constexpr int BLOCKS_PER_BATCH = 64;
constexpr int TPB = BLOCKS_PER_BATCH * THREADS;   // 16384 threads per batch
constexpr int ITERS = GROUPS / TPB;               // 4 groups (16 pixels) per thread

__global__ __launch_bounds__(THREADS, 4)   // allow ~128 VGPRs: keep 16 loads in flight
void seg_main(const float* __restrict__ pred,
              const float* __restrict__ tgt,
              float* __restrict__ bce_sum,
              unsigned* __restrict__ pc_g,   // [NB][NCL] pred counts
              unsigned* __restrict__ tc_g,   // [NB][NCL] tgt counts
              unsigned* __restrict__ tp_g)   // [NB][NCL] true positives
{
    const int b     = blockIdx.x & (NB - 1);       // one batch per block
    const int chunk = blockIdx.x >> 5;             // 0..63
    const int tib   = chunk * THREADS + threadIdx.x;

    // per-class stream pointers (planes are HW floats apart)
    const float* pp[NCL];
    const float* tq[NCL];
    {
        const size_t t0 = (size_t)b * NCL * HW + 4u * (size_t)tib;
#pragma unroll
        for (int c = 0; c < NCL; ++c) {
            pp[c] = pred + t0 + (size_t)c * HW;
            tq[c] = tgt  + t0 + (size_t)c * HW;
        }
    }

    float bce = 0.0f;
    unsigned pc[NCL] = {0, 0, 0, 0};
    unsigned tc[NCL] = {0, 0, 0, 0};
    unsigned tp[NCL] = {0, 0, 0, 0};

    // double-buffered pipeline: buffer parity it&1 holds iter it's data
    float4 pv[2][NCL], tv[2][NCL];
#pragma unroll
    for (int c = 0; c < NCL; ++c) {
        pv[0][c] = *reinterpret_cast<const float4*>(pp[c]);
        tv[0][c] = *reinterpret_cast<const float4*>(tq[c]);
    }

#pragma unroll
    for (int it = 0; it < ITERS; ++it) {
        const int cur = it & 1;
        const int nxt = cur ^ 1;
        if (it + 1 < ITERS) {
            const size_t soff = (size_t)(it + 1) * 4u * TPB;
#pragma unroll
            for (int c = 0; c < NCL; ++c) {
                pv[nxt][c] = *reinterpret_cast<const float4*>(pp[c] + soff);
                tv[nxt][c] = *reinterpret_cast<const float4*>(tq[c] + soff);
            }
        }
#pragma unroll
        for (int j = 0; j < 4; ++j) {
            float pj[NCL], tj[NCL];
#pragma unroll
            for (int c = 0; c < NCL; ++c) {
                pj[c] = (&pv[cur][c].x)[j];
                tj[c] = (&tv[cur][c].x)[j];
            }
            // first-occurrence argmax (strict >) matches jnp.argmax
            int cp = 0, ct = 0;
            float bp = pj[0], bt = tj[0];
#pragma unroll
            for (int c = 1; c < NCL; ++c) {
                if (pj[c] > bp) { bp = pj[c]; cp = c; }
                if (tj[c] > bt) { bt = tj[c]; ct = c; }
            }
#pragma unroll
            for (int c = 0; c < NCL; ++c) {
                pc[c] += (cp == c);
                tc[c] += (ct == c);
                tp[c] += ((cp == c) & (ct == c));
            }
            // BCE with logits, numerically stable
#pragma unroll
            for (int c = 0; c < NCL; ++c) {
                const float p = pj[c];
                bce += fmaxf(p, 0.0f) - p * tj[c]
                     + __logf(1.0f + __expf(-fabsf(p)));
            }
        }
    }

    // Pack 12 counters (each <=16 per thread, <=1024 after 64-lane sum) into
    // three u64 with 16-bit fields; butterfly-reduce across the wave.
    unsigned long long P = (unsigned long long)pc[0]
                         | ((unsigned long long)pc[1] << 16)
                         | ((unsigned long long)pc[2] << 32)
                         | ((unsigned long long)pc[3] << 48);
    unsigned long long T = (unsigned long long)tc[0]
                         | ((unsigned long long)tc[1] << 16)
                         | ((unsigned long long)tc[2] << 32)
                         | ((unsigned long long)tc[3] << 48);
    unsigned long long Q = (unsigned long long)tp[0]
                         | ((unsigned long long)tp[1] << 16)
                         | ((unsigned long long)tp[2] << 32)
                         | ((unsigned long long)tp[3] << 48);
#pragma unroll
    for (int o = 32; o > 0; o >>= 1) {
        bce += __shfl_xor(bce, o);
        P   += __shfl_xor(P, o);
        T   += __shfl_xor(T, o);
        Q   += __shfl_xor(Q, o);
    }
    if ((threadIdx.x & 63) == 0) {
        atomicAdd(bce_sum, bce);
#pragma unroll
        for (int c = 0; c < NCL; ++c) {
            atomicAdd(&pc_g[b * NCL + c], (unsigned)((P >> (16 * c)) & 0xFFFFu));
            atomicAdd(&tc_g[b * NCL + c], (unsigned)((T >> (16 * c)) & 0xFFFFu));
            atomicAdd(&tp_g[b * NCL + c], (unsigned)((Q >> (16 * c)) & 0xFFFFu));
        }
    }
}

__global__ void seg_final(const float* __restrict__ bce_sum,
                          const unsigned* __restrict__ pc_g,
                          const unsigned* __restrict__ tc_g,
                          const unsigned* __restrict__ tp_g,
                          float* __restrict__ out)
{
    const int t = threadIdx.x;
    float val = 0.0f;
    if (t < NB) {
        float iou = 0.0f;
        int present = 0;
#pragma unroll
        for (int c = 0; c < NCL; ++c) {
            const float P = (float)pc_g[t * NCL + c];
            const float T = (float)tc_g[t * NCL + c];
            const float K = (float)tp_g[t * NCL + c];
            const float den = P + T - K;
            if (den > 0.0f) iou += K / den;
            present += (tc_g[t * NCL + c] > 0u);
        }
        val = iou / (float)present;   // present >= 1 always (sum_c tgt_cnt = HW)
    }
#pragma unroll
    for (int o = 32; o > 0; o >>= 1) val += __shfl_xor(val, o);
    if (t == 0) {
        out[0] = bce_sum[0] / (float)((size_t)NB * NCL * HW);  // lseg
        out[1] = 1.0f - val / (float)NB;                       // liou
    }
}

extern "C" void kernel_launch(void* const* d_in, const int* in_sizes, int n_in,
                              void* d_out, int out_size, void* d_ws, size_t ws_size,
                              hipStream_t stream) {
    const float* pred = (const float*)d_in[0];
    const float* tgt  = (const float*)d_in[1];
    float* out = (float*)d_out;

    // workspace layout: [0,4): bce_sum (float); [256,...): 3 x 128 uint counters
    float*    bce_sum = (float*)d_ws;
    unsigned* pc_g    = (unsigned*)((char*)d_ws + 256);
    unsigned* tc_g    = pc_g + NB * NCL;
    unsigned* tp_g    = tc_g + NB * NCL;

    hipMemsetAsync(d_ws, 0, 256 + 3 * NB * NCL * sizeof(unsigned), stream);
    seg_main<<<NB * BLOCKS_PER_BATCH, THREADS, 0, stream>>>(pred, tgt, bce_sum,
                                                            pc_g, tc_g, tp_g);
    seg_final<<<1, 64, 0, stream>>>(bce_sum, pc_g, tc_g, tp_g, out);
}

// Round 3
// 286.793 us; speedup vs baseline: 1.1479x; 1.1045x over previous
//
#include <hip/hip_runtime.h>

// Problem: B=32, NC=4, H=512, W=512, fp32 in, two fp32 scalars out.
// lseg = mean BCE-with-logits; liou = 1 - mean_b( sum_c IoU(b,c) / present(b) ).
//
// R2 post-mortem: VGPR=48 proved the compiler collapsed the double buffer
// (64 regs of payload can't fit in 48) -> only ~2 loads in flight/wave ->
// 1.84 TB/s latency-bound. R3: pin the pipeline with sched_barrier(0) between
// the prefetch group and compute, launch_bounds(256,4) for a 128-VGPR budget,
// and deepen per-thread work (ITERS=8) so steady state dominates.

#define NB   32
#define NCL  4
constexpr int HW      = 512 * 512;       // 262144 pixels per (b,c) plane
constexpr int GROUPS  = HW / 4;          // 65536 float4-groups per batch
constexpr int THREADS = 256;
constexpr int BLOCKS_PER_BATCH = 32;
constexpr int TPB = BLOCKS_PER_BATCH * THREADS;   // 8192 threads per batch
constexpr int ITERS = GROUPS / TPB;               // 8 groups (32 pixels) per thread

__global__ __launch_bounds__(THREADS, 4)   // <=128 VGPR: room for 2x8 float4 payload
void seg_main(const float* __restrict__ pred,
              const float* __restrict__ tgt,
              float* __restrict__ bce_sum,
              unsigned* __restrict__ pc_g,   // [NB][NCL] pred counts
              unsigned* __restrict__ tc_g,   // [NB][NCL] tgt counts
              unsigned* __restrict__ tp_g)   // [NB][NCL] true positives
{
    const int b     = blockIdx.x & (NB - 1);       // one batch per block
    const int chunk = blockIdx.x >> 5;             // 0..BLOCKS_PER_BATCH-1
    const int tib   = chunk * THREADS + threadIdx.x;

    const float* pp[NCL];
    const float* tq[NCL];
    {
        const size_t t0 = (size_t)b * NCL * HW + 4u * (size_t)tib;
#pragma unroll
        for (int c = 0; c < NCL; ++c) {
            pp[c] = pred + t0 + (size_t)c * HW;
            tq[c] = tgt  + t0 + (size_t)c * HW;
        }
    }

    float bce = 0.0f;
    unsigned pc[NCL] = {0, 0, 0, 0};
    unsigned tc[NCL] = {0, 0, 0, 0};
    unsigned tp[NCL] = {0, 0, 0, 0};

    // double-buffered pipeline: buffer parity it&1 holds iter it's data
    float4 pv[2][NCL], tv[2][NCL];
#pragma unroll
    for (int c = 0; c < NCL; ++c) {
        pv[0][c] = *reinterpret_cast<const float4*>(pp[c]);
        tv[0][c] = *reinterpret_cast<const float4*>(tq[c]);
    }

#pragma unroll
    for (int it = 0; it < ITERS; ++it) {
        const int cur = it & 1;
        const int nxt = cur ^ 1;
        if (it + 1 < ITERS) {
            const size_t soff = (size_t)(it + 1) * 4u * TPB;
#pragma unroll
            for (int c = 0; c < NCL; ++c) {
                pv[nxt][c] = *reinterpret_cast<const float4*>(pp[c] + soff);
                tv[nxt][c] = *reinterpret_cast<const float4*>(tq[c] + soff);
            }
        }
        // Fence the scheduler: next-iter loads above may NOT sink into/below
        // the compute body. This is what keeps 8 loads in flight per wave.
        __builtin_amdgcn_sched_barrier(0);
#pragma unroll
        for (int j = 0; j < 4; ++j) {
            float pj[NCL], tj[NCL];
#pragma unroll
            for (int c = 0; c < NCL; ++c) {
                pj[c] = (&pv[cur][c].x)[j];
                tj[c] = (&tv[cur][c].x)[j];
            }
            // first-occurrence argmax (strict >) matches jnp.argmax
            int cp = 0, ct = 0;
            float bp = pj[0], bt = tj[0];
#pragma unroll
            for (int c = 1; c < NCL; ++c) {
                if (pj[c] > bp) { bp = pj[c]; cp = c; }
                if (tj[c] > bt) { bt = tj[c]; ct = c; }
            }
#pragma unroll
            for (int c = 0; c < NCL; ++c) {
                pc[c] += (cp == c);
                tc[c] += (ct == c);
                tp[c] += ((cp == c) & (ct == c));
            }
            // BCE with logits, numerically stable
#pragma unroll
            for (int c = 0; c < NCL; ++c) {
                const float p = pj[c];
                bce += fmaxf(p, 0.0f) - p * tj[c]
                     + __logf(1.0f + __expf(-fabsf(p)));
            }
        }
    }

    // Pack 12 counters (each <=32/thread, <=2048 after 64-lane sum) into
    // three u64 with 16-bit fields; butterfly-reduce across the wave.
    unsigned long long P = (unsigned long long)pc[0]
                         | ((unsigned long long)pc[1] << 16)
                         | ((unsigned long long)pc[2] << 32)
                         | ((unsigned long long)pc[3] << 48);
    unsigned long long T = (unsigned long long)tc[0]
                         | ((unsigned long long)tc[1] << 16)
                         | ((unsigned long long)tc[2] << 32)
                         | ((unsigned long long)tc[3] << 48);
    unsigned long long Q = (unsigned long long)tp[0]
                         | ((unsigned long long)tp[1] << 16)
                         | ((unsigned long long)tp[2] << 32)
                         | ((unsigned long long)tp[3] << 48);
#pragma unroll
    for (int o = 32; o > 0; o >>= 1) {
        bce += __shfl_xor(bce, o);
        P   += __shfl_xor(P, o);
        T   += __shfl_xor(T, o);
        Q   += __shfl_xor(Q, o);
    }
    if ((threadIdx.x & 63) == 0) {
        atomicAdd(bce_sum, bce);
#pragma unroll
        for (int c = 0; c < NCL; ++c) {
            atomicAdd(&pc_g[b * NCL + c], (unsigned)((P >> (16 * c)) & 0xFFFFu));
            atomicAdd(&tc_g[b * NCL + c], (unsigned)((T >> (16 * c)) & 0xFFFFu));
            atomicAdd(&tp_g[b * NCL + c], (unsigned)((Q >> (16 * c)) & 0xFFFFu));
        }
    }
}

__global__ void seg_final(const float* __restrict__ bce_sum,
                          const unsigned* __restrict__ pc_g,
                          const unsigned* __restrict__ tc_g,
                          const unsigned* __restrict__ tp_g,
                          float* __restrict__ out)
{
    const int t = threadIdx.x;
    float val = 0.0f;
    if (t < NB) {
        float iou = 0.0f;
        int present = 0;
#pragma unroll
        for (int c = 0; c < NCL; ++c) {
            const float P = (float)pc_g[t * NCL + c];
            const float T = (float)tc_g[t * NCL + c];
            const float K = (float)tp_g[t * NCL + c];
            const float den = P + T - K;
            if (den > 0.0f) iou += K / den;
            present += (tc_g[t * NCL + c] > 0u);
        }
        val = iou / (float)present;   // present >= 1 always (sum_c tgt_cnt = HW)
    }
#pragma unroll
    for (int o = 32; o > 0; o >>= 1) val += __shfl_xor(val, o);
    if (t == 0) {
        out[0] = bce_sum[0] / (float)((size_t)NB * NCL * HW);  // lseg
        out[1] = 1.0f - val / (float)NB;                       // liou
    }
}

extern "C" void kernel_launch(void* const* d_in, const int* in_sizes, int n_in,
                              void* d_out, int out_size, void* d_ws, size_t ws_size,
                              hipStream_t stream) {
    const float* pred = (const float*)d_in[0];
    const float* tgt  = (const float*)d_in[1];
    float* out = (float*)d_out;

    // workspace layout: [0,4): bce_sum (float); [256,...): 3 x 128 uint counters
    float*    bce_sum = (float*)d_ws;
    unsigned* pc_g    = (unsigned*)((char*)d_ws + 256);
    unsigned* tc_g    = pc_g + NB * NCL;
    unsigned* tp_g    = tc_g + NB * NCL;

    hipMemsetAsync(d_ws, 0, 256 + 3 * NB * NCL * sizeof(unsigned), stream);
    seg_main<<<NB * BLOCKS_PER_BATCH, THREADS, 0, stream>>>(pred, tgt, bce_sum,
                                                            pc_g, tc_g, tp_g);
    seg_final<<<1, 64, 0, stream>>>(bce_sum, pc_g, tc_g, tp_g, out);
}